// Round 4
// baseline (241.990 us; speedup 1.0000x reference)
//
#include <hip/hip_runtime.h>
#include <math.h>

#define D_DIM 256
#define HW 16384
#define C 19
#define N_PX 131072
#define EPS 1e-8f

#define S_SC  1048576.0f       // 2^20 fixed point for class sums (|sum| < ~500)
#define IS_S  (1.0f/1048576.0f)
#define U_SC  16777216.0f      // 2^24 fixed point for unit-vector sums (|sum| < ~30)
#define IS_U  (1.0f/16777216.0f)

// ws layout in 4-byte words
#define OFF_S    0        // int[4864] class sums Σf, fixed-point
#define OFF_U    4864     // int[4864] class unit sums Σf/||f||, fixed-point
#define OFF_CNT  9728     // int[19]   class counts
#define WS_ZERO  9747

// ---------- K0: zero class accumulators ----------
__global__ void k0_zero(int* __restrict__ ws) {
    int i = blockIdx.x * blockDim.x + threadIdx.x;
    if (i < WS_ZERO) ws[i] = 0;
}

// ---------- K1: single pass — counts, Σf, ||f||, Σf/||f|| ----------
// grid 1024: block owns 128 px. 256 thr = 64 px-pairs (q) × 4 d-quarters (dq).
// Each thread streams 64 d's of its px-pair as float2 (coalesced 512B/wave-load).
__global__ __launch_bounds__(256) void k1_pass(const float* __restrict__ in,
                                               const int* __restrict__ tgt,
                                               int* __restrict__ wsi) {
    __shared__ int sS[C * 257];      // stride 257: lanes at same d, distinct label -> distinct bank
    __shared__ int sU[C * 257];
    __shared__ int s_cnt[C];
    __shared__ __align__(16) float s_nfp[128 * 4];  // per-px partial ||f||^2, 4 d-quarters
    const int tid = threadIdx.x;
    const int q   = tid & 63;
    const int dq  = tid >> 6;

    for (int i = tid; i < C * 257; i += 256) { sS[i] = 0; sU[i] = 0; }
    if (tid < C) s_cnt[tid] = 0;
    __syncthreads();

    const int px0 = blockIdx.x << 7;          // 128 px per block (128 blocks per image: no b-crossing)
    const int b   = px0 >> 14;
    const int hwq = (px0 & (HW - 1)) + (q << 1);
    const int p   = px0 + (q << 1);
    const int la = tgt[p], lb = tgt[p + 1];
    if (dq == 0) { atomicAdd(&s_cnt[la], 1); atomicAdd(&s_cnt[lb], 1); }

    const float* base = in + (((size_t)(b * D_DIM + (dq << 6))) << 14) + hwq;

    // loop 1: ||f||^2 partials + S accumulation (S doesn't need the norm)
    float nfa = 0.f, nfb = 0.f;
    #pragma unroll
    for (int g = 0; g < 8; ++g) {
        float2 v[8];
        #pragma unroll
        for (int j = 0; j < 8; ++j)
            v[j] = *(const float2*)(base + ((size_t)(g * 8 + j) << 14));
        #pragma unroll
        for (int j = 0; j < 8; ++j) {
            const int dd = (dq << 6) + g * 8 + j;
            nfa += v[j].x * v[j].x; nfb += v[j].y * v[j].y;
            atomicAdd(&sS[la * 257 + dd], __float2int_rn(v[j].x * S_SC));
            atomicAdd(&sS[lb * 257 + dd], __float2int_rn(v[j].y * S_SC));
        }
    }
    s_nfp[(q << 3) + dq]     = nfa;   // px 2q
    s_nfp[(q << 3) + 4 + dq] = nfb;   // px 2q+1
    __syncthreads();

    const float4 na4 = *(const float4*)&s_nfp[q << 3];
    const float4 nb4 = *(const float4*)&s_nfp[(q << 3) + 4];
    const float nfs_a = na4.x + na4.y + na4.z + na4.w;
    const float nfs_b = nb4.x + nb4.y + nb4.z + nb4.w;
    const float sa = nfs_a > 0.f ? U_SC / sqrtf(nfs_a) : 0.f;
    const float sb = nfs_b > 0.f ? U_SC / sqrtf(nfs_b) : 0.f;

    // loop 2: re-read (L2/L3-hot) and accumulate unit-vector sums
    #pragma unroll
    for (int g = 0; g < 8; ++g) {
        float2 v[8];
        #pragma unroll
        for (int j = 0; j < 8; ++j)
            v[j] = *(const float2*)(base + ((size_t)(g * 8 + j) << 14));
        #pragma unroll
        for (int j = 0; j < 8; ++j) {
            const int dd = (dq << 6) + g * 8 + j;
            atomicAdd(&sU[la * 257 + dd], __float2int_rn(v[j].x * sa));
            atomicAdd(&sU[lb * 257 + dd], __float2int_rn(v[j].y * sb));
        }
    }
    __syncthreads();

    // merge to global (int atomics, 38/thread)
    for (int i = tid; i < C * 256; i += 256) {
        int c = i >> 8, d = i & 255;
        atomicAdd(&wsi[OFF_S + i], sS[c * 257 + d]);
        atomicAdd(&wsi[OFF_U + i], sU[c * 257 + d]);
    }
    if (tid < C) atomicAdd(&wsi[OFF_CNT + tid], s_cnt[tid]);
}

// ---------- K2: centers, norms, Gram/diff, sim, final (1 block, 8 waves) ----------
__global__ __launch_bounds__(512) void k2_final(const int* __restrict__ wsi,
                                                float* __restrict__ out) {
    __shared__ __align__(16) float s_cen[C * 260];  // 260 = 65 float4: rows 16B-aligned
    __shared__ __align__(16) float s_u[C * 260];
    __shared__ float s_nc[C];
    __shared__ float s_cntf[C];
    __shared__ float s_pair[C * C];
    __shared__ float s_sim[C];
    const int tid = threadIdx.x;

    if (tid < C) s_cntf[tid] = (float)wsi[OFF_CNT + tid];
    __syncthreads();
    for (int i = tid; i < C * 256; i += 512) {
        int c = i >> 8, d = i & 255;
        float icnt = 1.f / fmaxf(s_cntf[c], 1.f);
        s_cen[c * 260 + d] = (float)wsi[OFF_S + i] * IS_S * icnt;
        s_u[c * 260 + d]   = (float)wsi[OFF_U + i] * IS_U;
    }
    __syncthreads();
    if (tid < C) {
        float nsq = 0.f;
        for (int d = 0; d < D_DIM; ++d) {
            float x = s_cen[tid * 260 + d];
            nsq += x * x;
        }
        s_nc[tid] = sqrtf(nsq);
    }
    __syncthreads();
    if (tid < C * C) {                       // waves 0-5: Gram + diff pairs
        int i = tid / C, j = tid % C;
        const float4* ci = (const float4*)&s_cen[i * 260];
        const float4* cj = (const float4*)&s_cen[j * 260];
        float dot = 0.f;
        #pragma unroll 8
        for (int k = 0; k < 64; ++k) {
            float4 a = ci[k], bb = cj[k];
            dot += a.x * bb.x + a.y * bb.y + a.z * bb.z + a.w * bb.w;
        }
        float S = dot / fmaxf(s_nc[i] * s_nc[j], EPS);
        s_pair[tid] = (i == j) ? (1.f - S) : fmaxf(S, 0.f);
    } else if (tid >= 384 && tid < 384 + C) { // wave 6: sim dots, concurrent with Gram
        int i = tid - 384;
        const float4* ci = (const float4*)&s_cen[i * 260];
        const float4* ui = (const float4*)&s_u[i * 260];
        float dot = 0.f;
        #pragma unroll 8
        for (int k = 0; k < 64; ++k) {
            float4 a = ci[k], bb = ui[k];
            dot += a.x * bb.x + a.y * bb.y + a.z * bb.z + a.w * bb.w;
        }
        // sim_i = 1 - (Σ cos)/cnt = 1 - dot(center,U)/(nc*cnt)
        s_sim[i] = (s_cntf[i] > 0.f)
                 ? (1.f - dot / fmaxf(s_nc[i] * s_cntf[i], EPS)) : 0.f;
    }
    __syncthreads();
    if (tid < C) {
        float row = 0.f;
        for (int j = 0; j < C; ++j) row += s_pair[tid * C + j];
        s_pair[tid * C] = (s_cntf[tid] > 0.f) ? (row * (1.f / (float)C)) : 0.f;
    }
    __syncthreads();
    if (tid == 0) {
        float tot = 0.f;
        for (int i = 0; i < C; ++i) tot += s_pair[i * C] + s_sim[i];
        out[0] = tot;
    }
}

extern "C" void kernel_launch(void* const* d_in, const int* in_sizes, int n_in,
                              void* d_out, int out_size, void* d_ws, size_t ws_size,
                              hipStream_t stream) {
    const float* in  = (const float*)d_in[0];
    const int*   tgt = (const int*)d_in[1];
    float* out = (float*)d_out;
    int*   wsi = (int*)d_ws;

    k0_zero<<<39, 256, 0, stream>>>(wsi);
    k1_pass<<<1024, 256, 0, stream>>>(in, tgt, wsi);
    k2_final<<<1, 512, 0, stream>>>(wsi, out);
}

// Round 5
// 229.551 us; speedup vs baseline: 1.0542x; 1.0542x over previous
//
#include <hip/hip_runtime.h>
#include <math.h>

#define D_DIM 256
#define HW 16384
#define C 19
#define N_PX 131072
#define EPS 1e-8f

#define S_SC  1048576.0f       // 2^20 fixed point for class sums (|sum| < ~500)
#define IS_S  (1.0f/1048576.0f)
#define U_SC  16777216.0f      // 2^24 fixed point for unit-vector sums (|sum| < ~30)
#define IS_U  (1.0f/16777216.0f)

// ws layout in 4-byte words
#define OFF_S    0        // int[4864] class sums Σf, fixed-point
#define OFF_U    4864     // int[4864] class unit sums Σf/||f||, fixed-point
#define OFF_CNT  9728     // int[19]   class counts (+13 pad words to 9760)
#define WS_ZERO  9760
#define OFF_PART 9760     // int[512][9760] per-block partials (20 MB)
#define PSTRIDE  9760     // row stride, 16B-divisible
#define G1       512

// ---------- K0: zero final accumulators ----------
__global__ void k0_zero(int* __restrict__ ws) {
    int i = blockIdx.x * blockDim.x + threadIdx.x;
    if (i < WS_ZERO) ws[i] = 0;
}

// ---------- K1: single pass — counts, Σf, ||f||, Σf/||f||; plain partial-row writeout ----------
// grid 512: block owns 256 px (2 rounds of 128). 256 thr = 64 px-pairs (q) × 4 d-quarters (dq).
__global__ __launch_bounds__(256) void k1_pass(const float* __restrict__ in,
                                               const int* __restrict__ tgt,
                                               int* __restrict__ wsi) {
    __shared__ int sS[C * 257];      // stride 257: distinct labels -> distinct banks
    __shared__ int sU[C * 257];
    __shared__ int s_cnt[C];
    __shared__ __align__(16) float s_nfp[128 * 4];  // per-px partial ||f||^2, 4 d-quarters
    const int tid = threadIdx.x;
    const int q   = tid & 63;
    const int dq  = tid >> 6;

    for (int i = tid; i < C * 257; i += 256) { sS[i] = 0; sU[i] = 0; }
    if (tid < C) s_cnt[tid] = 0;
    __syncthreads();

    const int px0 = blockIdx.x << 8;          // 256 px per block (64 blocks/image: no b-crossing)
    const int b   = px0 >> 14;

    #pragma unroll
    for (int r = 0; r < 2; ++r) {
        const int hwq = (px0 & (HW - 1)) + (r << 7) + (q << 1);
        const int p   = px0 + (r << 7) + (q << 1);
        const int la = tgt[p], lb = tgt[p + 1];
        if (dq == 0) { atomicAdd(&s_cnt[la], 1); atomicAdd(&s_cnt[lb], 1); }

        const float* base = in + (((size_t)(b * D_DIM + (dq << 6))) << 14) + hwq;

        // loop 1: ||f||^2 partials only (pure load + FMA)
        float nfa = 0.f, nfb = 0.f;
        #pragma unroll
        for (int g = 0; g < 8; ++g) {
            float2 v[8];
            #pragma unroll
            for (int j = 0; j < 8; ++j)
                v[j] = *(const float2*)(base + ((size_t)(g * 8 + j) << 14));
            #pragma unroll
            for (int j = 0; j < 8; ++j) {
                nfa += v[j].x * v[j].x; nfb += v[j].y * v[j].y;
            }
        }
        s_nfp[(q << 3) + dq]     = nfa;   // px 2q
        s_nfp[(q << 3) + 4 + dq] = nfb;   // px 2q+1
        __syncthreads();

        const float4 na4 = *(const float4*)&s_nfp[q << 3];
        const float4 nb4 = *(const float4*)&s_nfp[(q << 3) + 4];
        const float nfs_a = na4.x + na4.y + na4.z + na4.w;
        const float nfs_b = nb4.x + nb4.y + nb4.z + nb4.w;
        const float sa = nfs_a > 0.f ? U_SC / sqrtf(nfs_a) : 0.f;
        const float sb = nfs_b > 0.f ? U_SC / sqrtf(nfs_b) : 0.f;

        // loop 2: re-read (L2/L3-hot) and accumulate S and U into LDS (native int atomics)
        #pragma unroll
        for (int g = 0; g < 8; ++g) {
            float2 v[8];
            #pragma unroll
            for (int j = 0; j < 8; ++j)
                v[j] = *(const float2*)(base + ((size_t)(g * 8 + j) << 14));
            #pragma unroll
            for (int j = 0; j < 8; ++j) {
                const int dd = (dq << 6) + g * 8 + j;
                atomicAdd(&sS[la * 257 + dd], __float2int_rn(v[j].x * S_SC));
                atomicAdd(&sS[lb * 257 + dd], __float2int_rn(v[j].y * S_SC));
                atomicAdd(&sU[la * 257 + dd], __float2int_rn(v[j].x * sa));
                atomicAdd(&sU[lb * 257 + dd], __float2int_rn(v[j].y * sb));
            }
        }
        __syncthreads();   // protect s_nfp reuse + order atomics before writeout
    }

    // plain coalesced writeout of this block's partial row (NO global atomics)
    int* __restrict__ row = wsi + OFF_PART + (size_t)blockIdx.x * PSTRIDE;
    for (int i = tid; i < C * 256; i += 256) {
        int c = i >> 8, d = i & 255;
        row[OFF_S + i] = sS[c * 257 + d];
        row[OFF_U + i] = sU[c * 257 + d];
    }
    if (tid < C)                 row[OFF_CNT + tid] = s_cnt[tid];
    else if (tid < 32)           row[OFF_CNT + tid] = 0;   // pad to 9760
}

// ---------- K1b: reduce 512 partial rows -> final arrays ----------
// grid (10, 32): block sums 16 rows for 1024 columns (int4), 4 atomics/thread to finish.
__global__ __launch_bounds__(256) void k1b_reduce(int* __restrict__ wsi) {
    const int col4 = blockIdx.x * 256 + threadIdx.x;     // int4 column index
    if (col4 >= PSTRIDE / 4) return;
    const int4* base = (const int4*)(wsi + OFF_PART)
                     + (size_t)blockIdx.y * 16 * (PSTRIDE / 4) + col4;
    int4 acc = {0, 0, 0, 0};
    #pragma unroll
    for (int r = 0; r < 16; ++r) {
        int4 v = base[(size_t)r * (PSTRIDE / 4)];
        acc.x += v.x; acc.y += v.y; acc.z += v.z; acc.w += v.w;
    }
    atomicAdd(&wsi[col4 * 4 + 0], acc.x);
    atomicAdd(&wsi[col4 * 4 + 1], acc.y);
    atomicAdd(&wsi[col4 * 4 + 2], acc.z);
    atomicAdd(&wsi[col4 * 4 + 3], acc.w);
}

// ---------- K2: centers, norms, Gram/diff, sim, final (1 block, 8 waves) ----------
__global__ __launch_bounds__(512) void k2_final(const int* __restrict__ wsi,
                                                float* __restrict__ out) {
    __shared__ __align__(16) float s_cen[C * 260];  // 260 = 65 float4: rows 16B-aligned
    __shared__ __align__(16) float s_u[C * 260];
    __shared__ float s_nc[C];
    __shared__ float s_cntf[C];
    __shared__ float s_pair[C * C];
    __shared__ float s_sim[C];
    const int tid = threadIdx.x;

    if (tid < C) s_cntf[tid] = (float)wsi[OFF_CNT + tid];
    __syncthreads();
    for (int i = tid; i < C * 256; i += 512) {
        int c = i >> 8, d = i & 255;
        float icnt = 1.f / fmaxf(s_cntf[c], 1.f);
        s_cen[c * 260 + d] = (float)wsi[OFF_S + i] * IS_S * icnt;
        s_u[c * 260 + d]   = (float)wsi[OFF_U + i] * IS_U;
    }
    __syncthreads();
    if (tid < C) {
        float nsq = 0.f;
        for (int d = 0; d < D_DIM; ++d) {
            float x = s_cen[tid * 260 + d];
            nsq += x * x;
        }
        s_nc[tid] = sqrtf(nsq);
    }
    __syncthreads();
    if (tid < C * C) {                       // waves 0-5: Gram + diff pairs
        int i = tid / C, j = tid % C;
        const float4* ci = (const float4*)&s_cen[i * 260];
        const float4* cj = (const float4*)&s_cen[j * 260];
        float dot = 0.f;
        #pragma unroll 8
        for (int k = 0; k < 64; ++k) {
            float4 a = ci[k], bb = cj[k];
            dot += a.x * bb.x + a.y * bb.y + a.z * bb.z + a.w * bb.w;
        }
        float S = dot / fmaxf(s_nc[i] * s_nc[j], EPS);
        s_pair[tid] = (i == j) ? (1.f - S) : fmaxf(S, 0.f);
    } else if (tid >= 384 && tid < 384 + C) { // wave 6: sim dots, concurrent with Gram
        int i = tid - 384;
        const float4* ci = (const float4*)&s_cen[i * 260];
        const float4* ui = (const float4*)&s_u[i * 260];
        float dot = 0.f;
        #pragma unroll 8
        for (int k = 0; k < 64; ++k) {
            float4 a = ci[k], bb = ui[k];
            dot += a.x * bb.x + a.y * bb.y + a.z * bb.z + a.w * bb.w;
        }
        // sim_i = 1 - (Σ cos)/cnt = 1 - dot(center,U)/(nc*cnt)
        s_sim[i] = (s_cntf[i] > 0.f)
                 ? (1.f - dot / fmaxf(s_nc[i] * s_cntf[i], EPS)) : 0.f;
    }
    __syncthreads();
    if (tid < C) {
        float row = 0.f;
        for (int j = 0; j < C; ++j) row += s_pair[tid * C + j];
        s_pair[tid * C] = (s_cntf[tid] > 0.f) ? (row * (1.f / (float)C)) : 0.f;
    }
    __syncthreads();
    if (tid == 0) {
        float tot = 0.f;
        for (int i = 0; i < C; ++i) tot += s_pair[i * C] + s_sim[i];
        out[0] = tot;
    }
}

extern "C" void kernel_launch(void* const* d_in, const int* in_sizes, int n_in,
                              void* d_out, int out_size, void* d_ws, size_t ws_size,
                              hipStream_t stream) {
    const float* in  = (const float*)d_in[0];
    const int*   tgt = (const int*)d_in[1];
    float* out = (float*)d_out;
    int*   wsi = (int*)d_ws;

    k0_zero<<<39, 256, 0, stream>>>(wsi);
    k1_pass<<<G1, 256, 0, stream>>>(in, tgt, wsi);
    k1b_reduce<<<dim3(10, 32), 256, 0, stream>>>(wsi);
    k2_final<<<1, 512, 0, stream>>>(wsi, out);
}